// Round 3
// baseline (183.170 us; speedup 1.0000x reference)
//
#include <hip/hip_runtime.h>

// Hierarchical softmax: B=4096, NHID=512, BR=32, DEPTH=3, V=32768.
// bucket g = lab>>5. node0=0 (step g>>5), node1=1+(g>>5) (step g&31),
// node2=33+g (step lab&31). out[b] = prod_k softmax(x_b @ W[node_k])[step_k]
//
// R12: R11 (580 GB/s, 45 MB traffic) was still latency-bound because the
// counted-vmcnt pipeline was structurally defeated: (1) __syncthreads after
// x-staging drains vmcnt(0) every sample-iteration, killing the prime;
// (2) vmcnt retires IN ORDER, so scan/staging loads issued after the prime
// force-drain it when consumed; (3) the compiler can't prove the C-level
// ds_reads of wb[] don't race the outstanding global_load_lds DMAs and
// inserts its own vmcnt(0) before them, collapsing depth to <=1.
// Fix: hermetic phases. scan -> x-stage+barrier (no DMAs live) -> prime 3
// buffers -> 16-chunk loop where ALL reads of DMA'd LDS are inline-asm
// ds_read_b128 (invisible to the waitcnt pass), waits are hand-counted
// vmcnt(8/4/0)+lgkmcnt(0) each pinned with sched_barrier(0) (rule 18), and
// ISSUE(c+3) sits between the lgkm wait and the FMAs. Depth 3 x 4 KB/wave
// in flight, zero barriers and zero foreign VMEM inside the loop.

#define NHID   512
#define BR     32
#define BATCH  4096
#define NBUCK  1024
#define SMAX   8
#define CAP    64              // Poisson(4) max ~16; 64 is safe
#define CROWS  32              // W rows per chunk
#define CFLT   (CROWS * BR)    // floats per chunk = 1024 (4 KB)
#define NCHUNK (NHID / CROWS)  // 16
#define NBUF   3               // per-wave chunk buffers (depth-3 pipeline)

#define FMA4(A, xv, wv_) do { \
    (A).x = fmaf((xv), (wv_).x, (A).x); \
    (A).y = fmaf((xv), (wv_).y, (A).y); \
    (A).z = fmaf((xv), (wv_).z, (A).z); \
    (A).w = fmaf((xv), (wv_).w, (A).w); } while (0)

// async global->LDS, 16 B per lane (wave-uniform LDS base, HW adds lane*16)
__device__ __forceinline__ void gload_lds16(const float* g, float* l) {
    __builtin_amdgcn_global_load_lds(
        (const __attribute__((address_space(1))) void*)g,
        (__attribute__((address_space(3))) void*)l, 16, 0, 0);
}

// LDS byte offset of a __shared__ object (generic -> AS3 -> 32-bit)
__device__ __forceinline__ uint32_t lds_a(const void* p) {
    return (uint32_t)(uintptr_t)(const __attribute__((address_space(3))) void*)p;
}

// asm ds_read_b128: invisible to the compiler's waitcnt pass -> it cannot
// insert a conservative vmcnt(0) against the in-flight DMAs.
__device__ __forceinline__ float4 dsr128(uint32_t a) {
    float4 r;
    asm volatile("ds_read_b128 %0, %1" : "=v"(r) : "v"(a));
    return r;
}

__global__ __launch_bounds__(192) void hsm_bucket(
    const float* __restrict__ inputs,
    const int* __restrict__ labels,
    const float* __restrict__ W,
    float* __restrict__ out)
{
    __shared__ float xsT[NHID * SMAX];        // 16 KB, xsT[h][s0..7]
    __shared__ float wb[3][NBUF][CFLT];       // 36 KB: per-wave W ring
    __shared__ float pk[3][SMAX];
    __shared__ int   sids[CAP];
    __shared__ int   slab[CAP];
    __shared__ int   scnt;

    const int g    = blockIdx.x;
    const int tid  = threadIdx.x;
    const int k    = tid >> 6;    // wave = tree level
    const int lane = tid & 63;
    const int colg = lane & 7;    // float4 column group
    const int hsel = lane >> 3;   // h strip: h = 8i + hsel

    const int node   = (k == 0) ? 0 : (k == 1) ? 1 + (g >> 5) : 33 + g;
    const int step01 = (k == 0) ? (g >> 5) : (g & 31);

    const float* wglob = W + (size_t)node * (NHID * BR) + lane * 4;

    #define ISSUE(c, b) do { \
        const float* gs_ = wglob + (size_t)(c) * CFLT; \
        float* ld_ = wb[k][(b)]; \
        gload_lds16(gs_,       ld_); \
        gload_lds16(gs_ + 256, ld_ + 256); \
        gload_lds16(gs_ + 512, ld_ + 512); \
        gload_lds16(gs_ + 768, ld_ + 768); } while (0)

    if (tid == 0) scnt = 0;
    __syncthreads();

    // ---- phase A: self-discovery scan (no DMAs outstanding yet) ----
    const int4* l4 = (const int4*)labels;
    for (int i = tid; i < BATCH / 4; i += 192) {
        const int4 v = l4[i];
        if ((v.x >> 5) == g) { int p = atomicAdd(&scnt, 1); if (p < CAP) { sids[p] = 4*i;   slab[p] = v.x; } }
        if ((v.y >> 5) == g) { int p = atomicAdd(&scnt, 1); if (p < CAP) { sids[p] = 4*i+1; slab[p] = v.y; } }
        if ((v.z >> 5) == g) { int p = atomicAdd(&scnt, 1); if (p < CAP) { sids[p] = 4*i+2; slab[p] = v.z; } }
        if ((v.w >> 5) == g) { int p = atomicAdd(&scnt, 1); if (p < CAP) { sids[p] = 4*i+3; slab[p] = v.w; } }
    }
    __syncthreads();
    const int mt = min(scnt, CAP);
    if (mt == 0) return;      // no DMAs issued yet: clean exit

    // per-lane LDS read bases (bytes)
    const uint32_t wA0 = lds_a(&wb[k][0][0]) + (uint32_t)lane * 16;
    const uint32_t wA1 = lds_a(&wb[k][1][0]) + (uint32_t)lane * 16;
    const uint32_t wA2 = lds_a(&wb[k][2][0]) + (uint32_t)lane * 16;
    const uint32_t xA  = lds_a(xsT) + (uint32_t)hsel * 32;

    for (int c0 = 0; c0 < mt; c0 += SMAX) {
        if (c0 > 0) __syncthreads();   // rare; xsT/pk reuse fence

        // ---- phase B: stage xsT[h][0..7]; no DMAs live, barrier is free ----
        for (int h = tid; h < NHID; h += 192) {
            float v[SMAX];
            #pragma unroll
            for (int s = 0; s < SMAX; ++s) {
                const int q = c0 + s;
                v[s] = (q < mt) ? inputs[(size_t)sids[q] * NHID + h] : 0.0f;
            }
            float4* dst = (float4*)&xsT[h * SMAX];
            dst[0] = make_float4(v[0], v[1], v[2], v[3]);
            dst[1] = make_float4(v[4], v[5], v[6], v[7]);
        }
        __syncthreads();

        // ---- phase C: prime 3 chunks, then hermetic chunk pipeline ----
        ISSUE(0, 0); ISSUE(1, 1); ISSUE(2, 2);

        float4 acc[SMAX];
        #pragma unroll
        for (int s = 0; s < SMAX; ++s) acc[s] = make_float4(0, 0, 0, 0);

        #pragma unroll
        for (int c = 0; c < NCHUNK; ++c) {
            // drain exactly chunk c (12 -> 8 outstanding in steady state)
            if (c == NCHUNK - 1)      asm volatile("s_waitcnt vmcnt(0)" ::: "memory");
            else if (c == NCHUNK - 2) asm volatile("s_waitcnt vmcnt(4)" ::: "memory");
            else                      asm volatile("s_waitcnt vmcnt(8)" ::: "memory");
            __builtin_amdgcn_sched_barrier(0);

            const uint32_t wbase = (c % NBUF == 0) ? wA0 : (c % NBUF == 1) ? wA1 : wA2;
            const uint32_t xbase = xA + (uint32_t)(c * CROWS) * 32;

            float4 wv[4], xa[4], xb[4];
            #pragma unroll
            for (int j = 0; j < 4; ++j) {
                wv[j] = dsr128(wbase + (uint32_t)j * 1024);
                xa[j] = dsr128(xbase + (uint32_t)j * 256);
                xb[j] = dsr128(xbase + (uint32_t)j * 256 + 16);
            }
            asm volatile("s_waitcnt lgkmcnt(0)" ::: "memory");
            __builtin_amdgcn_sched_barrier(0);

            if (c + NBUF < NCHUNK) ISSUE(c + NBUF, c % NBUF);  // refill ring
            __builtin_amdgcn_sched_barrier(0);

            #pragma unroll
            for (int j = 0; j < 4; ++j) {
                FMA4(acc[0], xa[j].x, wv[j]); FMA4(acc[1], xa[j].y, wv[j]);
                FMA4(acc[2], xa[j].z, wv[j]); FMA4(acc[3], xa[j].w, wv[j]);
                FMA4(acc[4], xb[j].x, wv[j]); FMA4(acc[5], xb[j].y, wv[j]);
                FMA4(acc[6], xb[j].z, wv[j]); FMA4(acc[7], xb[j].w, wv[j]);
            }
        }

        // butterfly-reduce over hsel (masks 8,16,32): all lanes full sums
        #pragma unroll
        for (int s = 0; s < SMAX; ++s) {
            #pragma unroll
            for (int mm = 8; mm <= 32; mm <<= 1) {
                acc[s].x += __shfl_xor(acc[s].x, mm);
                acc[s].y += __shfl_xor(acc[s].y, mm);
                acc[s].z += __shfl_xor(acc[s].z, mm);
                acc[s].w += __shfl_xor(acc[s].w, mm);
            }
        }

        // per-sample softmax over 32 logits (8 colg lanes x 4 comps)
        #pragma unroll
        for (int s = 0; s < SMAX; ++s) {
            float4 a = acc[s];
            float mx = fmaxf(fmaxf(a.x, a.y), fmaxf(a.z, a.w));
            #pragma unroll
            for (int mm = 1; mm <= 4; mm <<= 1) mx = fmaxf(mx, __shfl_xor(mx, mm));
            float es = expf(a.x - mx) + expf(a.y - mx) + expf(a.z - mx) + expf(a.w - mx);
            #pragma unroll
            for (int mm = 1; mm <= 4; mm <<= 1) es += __shfl_xor(es, mm);

            const int step = (k == 2) ? (slab[c0 + s] & 31) : step01;
            const int e = step & 3;
            const float vv = (e == 0) ? a.x : (e == 1) ? a.y : (e == 2) ? a.z : a.w;
            const float sl = __shfl(vv, step >> 2);
            const float p = expf(sl - mx) / es;
            if (lane == 0) pk[k][s] = p;
        }
        __syncthreads();

        if (tid < SMAX && c0 + tid < mt)
            out[sids[c0 + tid]] = pk[0][tid] * pk[1][tid] * pk[2][tid];
    }
    #undef ISSUE
}

extern "C" void kernel_launch(void* const* d_in, const int* in_sizes, int n_in,
                              void* d_out, int out_size, void* d_ws, size_t ws_size,
                              hipStream_t stream)
{
    const float* inputs = (const float*)d_in[0];
    const int*   labels = (const int*)d_in[1];
    const float* W      = (const float*)d_in[2];
    float* out = (float*)d_out;

    hsm_bucket<<<dim3(NBUCK), dim3(192), 0, stream>>>(inputs, labels, W, out);
}

// Round 4
// 179.710 us; speedup vs baseline: 1.0193x; 1.0193x over previous
//
#include <hip/hip_runtime.h>

// Hierarchical softmax: B=4096, NHID=512, BR=32, DEPTH=3, V=32768.
// bucket g = lab>>5. node0=0 (step g>>5), node1=1+(g>>5) (step g&31),
// node2=33+g (step lab&31). out[b] = prod_k softmax(x_b @ W[node_k])[step_k]
//
// R13: R10-R12 all failed to create per-wave MLP through the compiler's
// waitcnt machinery (register dbuf serialized; compiler vmcnt(0) before LDS
// reads of DMA'd buffers; hermetic asm pipeline cost occupancy). Pivot to
// TLP: 256-thread blocks (4 waves), work = 24 jobs (3 levels x 8 h-octants
// of 64 rows). Wave w runs 6 jobs with a static wA/wB register prefetch of
// the next job's 8 coalesced float4 W loads -- plain loads, in-order vmcnt:
// consuming wA waits only wA while wB stays in flight. ~12 waves/CU x 4 KB
// prefetch ~= 48 KB/CU in flight > the ~30 KB needed to saturate the CU's
// HBM share; no asm, no global_load_lds, no W in LDS.
// Per job: 64 FMA4/lane -> butterfly over hsel (masks 8/16/32) -> lanes
// hsel==0 write part[job][8][32] (deterministic) -> tree reduce -> per-wave
// softmax (rows split 2/wave-half) -> out = p0*p1*p2.
// LDS ~53 KB (xsT padded [512][12]: conflict-free b128 reads), 3 blocks/CU.

#define NHID  512
#define BR    32
#define BATCH 4096
#define NBUCK 1024
#define SMAX  8
#define CAP   64    // Poisson(4) max ~16; 64 is safe

#define FMA4(A, xv, wv_) do { \
    (A).x = fmaf((xv), (wv_).x, (A).x); \
    (A).y = fmaf((xv), (wv_).y, (A).y); \
    (A).z = fmaf((xv), (wv_).z, (A).z); \
    (A).w = fmaf((xv), (wv_).w, (A).w); } while (0)

// W float4 pointer for job j (k = j>>3, oct = j&7), fixed (hsel, colg) lane
__device__ __forceinline__ const float4* wptr(const float* W, int g, int j,
                                              int hsel, int colg) {
    const int k    = j >> 3;
    const int node = (k == 0) ? 0 : (k == 1) ? 1 + (g >> 5) : 33 + g;
    return (const float4*)(W + (size_t)node * (NHID * BR))
           + ((j & 7) * 64 + hsel) * 8 + colg;
}

__device__ __forceinline__ void loadw(float4 (&buf)[8], const float4* wp) {
    #pragma unroll
    for (int jj = 0; jj < 8; ++jj) buf[jj] = wp[jj * 64];  // 8 rows, stride 8*8 f4
}

__device__ __forceinline__ void dojob(const float4 (&buf)[8], int j, int hsel,
                                      int colg, const float4* xsT4, float4* part4) {
    float4 acc[8];
    #pragma unroll
    for (int s = 0; s < 8; ++s) acc[s] = make_float4(0, 0, 0, 0);

    const int oct = j & 7;
    #pragma unroll
    for (int jj = 0; jj < 8; ++jj) {
        const int row = oct * 64 + hsel + 8 * jj;
        const float4 xa = xsT4[row * 3];      // samples 0..3 at h=row
        const float4 xb = xsT4[row * 3 + 1];  // samples 4..7
        FMA4(acc[0], xa.x, buf[jj]); FMA4(acc[1], xa.y, buf[jj]);
        FMA4(acc[2], xa.z, buf[jj]); FMA4(acc[3], xa.w, buf[jj]);
        FMA4(acc[4], xb.x, buf[jj]); FMA4(acc[5], xb.y, buf[jj]);
        FMA4(acc[6], xb.z, buf[jj]); FMA4(acc[7], xb.w, buf[jj]);
    }
    // butterfly over hsel (masks 8,16,32): all lanes hold full 64-row sums
    #pragma unroll
    for (int s = 0; s < 8; ++s) {
        #pragma unroll
        for (int mm = 8; mm <= 32; mm <<= 1) {
            acc[s].x += __shfl_xor(acc[s].x, mm);
            acc[s].y += __shfl_xor(acc[s].y, mm);
            acc[s].z += __shfl_xor(acc[s].z, mm);
            acc[s].w += __shfl_xor(acc[s].w, mm);
        }
    }
    if (hsel == 0) {   // 8 lanes (colg 0..7): 128 B contiguous per s, no conflict
        float4* pp = part4 + j * 64 + colg;
        #pragma unroll
        for (int s = 0; s < 8; ++s) pp[s * 8] = acc[s];
    }
}

__global__ __launch_bounds__(256) void hsm_bucket(
    const float* __restrict__ inputs,
    const int* __restrict__ labels,
    const float* __restrict__ W,
    float* __restrict__ out)
{
    __shared__ float xsT[NHID * 12];    // 24 KB: [h][s0..7, pad4] (48 B rows)
    __shared__ float part[24 * 256];    // 24 KB: [job][s][c]
    __shared__ float logits[768];       // 3 KB: [k][s][c]
    __shared__ float pkv[24];           // [k*8+s]
    __shared__ int   sids[CAP];
    __shared__ int   slab[CAP];
    __shared__ int   scnt;

    const int g    = blockIdx.x;
    const int tid  = threadIdx.x;
    const int w    = tid >> 6;     // wave 0..3
    const int lane = tid & 63;
    const int colg = lane & 7;     // float4 column group
    const int hsel = lane >> 3;    // h strip within 64-row octant

    if (tid == 0) scnt = 0;
    __syncthreads();

    // ---- scan all labels (int4), compact matches into sids/slab ----
    const int4* l4 = (const int4*)labels;
    #pragma unroll
    for (int r = 0; r < BATCH / 4 / 256; ++r) {
        const int i = tid + 256 * r;
        const int4 v = l4[i];
        if ((v.x >> 5) == g) { int p = atomicAdd(&scnt, 1); if (p < CAP) { sids[p] = 4*i;   slab[p] = v.x; } }
        if ((v.y >> 5) == g) { int p = atomicAdd(&scnt, 1); if (p < CAP) { sids[p] = 4*i+1; slab[p] = v.y; } }
        if ((v.z >> 5) == g) { int p = atomicAdd(&scnt, 1); if (p < CAP) { sids[p] = 4*i+2; slab[p] = v.z; } }
        if ((v.w >> 5) == g) { int p = atomicAdd(&scnt, 1); if (p < CAP) { sids[p] = 4*i+3; slab[p] = v.w; } }
    }
    __syncthreads();
    const int mt = min(scnt, CAP);
    if (mt == 0) return;

    const float4* xsT4  = (const float4*)xsT;
    float4*       part4 = (float4*)part;

    for (int c0 = 0; c0 < mt; c0 += SMAX) {
        // ---- stage xsT[h][0..7] (zero-pad unused slots) ----
        int sd[SMAX];
        #pragma unroll
        for (int s = 0; s < SMAX; ++s)
            sd[s] = (c0 + s < mt) ? sids[c0 + s] : -1;
        for (int h = tid; h < NHID; h += 256) {
            float v[SMAX];
            #pragma unroll
            for (int s = 0; s < SMAX; ++s)
                v[s] = (sd[s] >= 0) ? inputs[(size_t)sd[s] * NHID + h] : 0.0f;
            float4* dst = (float4*)&xsT[h * 12];
            dst[0] = make_float4(v[0], v[1], v[2], v[3]);
            dst[1] = make_float4(v[4], v[5], v[6], v[7]);
        }
        __syncthreads();

        // ---- 6 jobs per wave, static double-buffered W prefetch ----
        {
            float4 wA[8], wB[8];
            loadw(wA, wptr(W, g, w, hsel, colg));
            #pragma unroll
            for (int i = 0; i < 6; ++i) {
                const int j = w + 4 * i;
                if ((i & 1) == 0) {
                    if (i < 5) loadw(wB, wptr(W, g, w + 4 * (i + 1), hsel, colg));
                    dojob(wA, j, hsel, colg, xsT4, part4);
                } else {
                    if (i < 5) loadw(wA, wptr(W, g, w + 4 * (i + 1), hsel, colg));
                    dojob(wB, j, hsel, colg, xsT4, part4);
                }
            }
        }
        __syncthreads();

        // ---- reduce 8 octant partials -> logits[768] ----
        #pragma unroll
        for (int o = 0; o < 3; ++o) {
            const int idx = tid + 256 * o;          // = k*256 + s*32 + c
            float sum = 0.0f;
            #pragma unroll
            for (int oc = 0; oc < 8; ++oc)
                sum += part[((idx >> 8) * 8 + oc) * 256 + (idx & 255)];
            logits[idx] = sum;
        }
        __syncthreads();

        // ---- softmax: 24 rows of 32; wave w does rows 6w..6w+5 (2/pass) ----
        {
            const int l32  = lane & 31;
            const int half = lane >> 5;
            #pragma unroll
            for (int rr = 0; rr < 3; ++rr) {
                const int row = w * 6 + rr * 2 + half;
                const int kk = row >> 3, ss = row & 7;
                float v = logits[row * 32 + l32];
                float mx = v;
                #pragma unroll
                for (int mm = 1; mm <= 16; mm <<= 1) mx = fmaxf(mx, __shfl_xor(mx, mm));
                const float e = expf(v - mx);
                float es = e;
                #pragma unroll
                for (int mm = 1; mm <= 16; mm <<= 1) es += __shfl_xor(es, mm);
                const int step = (kk == 2) ? (slab[c0 + ss] & 31)
                               : (kk == 0) ? (g >> 5) : (g & 31);
                if (l32 == step) pkv[row] = e / es;
            }
        }
        __syncthreads();

        if (tid < SMAX && c0 + tid < mt)
            out[sids[c0 + tid]] = pkv[tid] * pkv[8 + tid] * pkv[16 + tid];
        __syncthreads();   // protect xsT/part/logits/pkv before next pass
    }
}

extern "C" void kernel_launch(void* const* d_in, const int* in_sizes, int n_in,
                              void* d_out, int out_size, void* d_ws, size_t ws_size,
                              hipStream_t stream)
{
    const float* inputs = (const float*)d_in[0];
    const int*   labels = (const int*)d_in[1];
    const float* W      = (const float*)d_in[2];
    float* out = (float*)d_out;

    hsm_bucket<<<dim3(NBUCK), dim3(256), 0, stream>>>(inputs, labels, W, out);
}

// Round 5
// 167.863 us; speedup vs baseline: 1.0912x; 1.0706x over previous
//
#include <hip/hip_runtime.h>

// Hierarchical softmax: B=4096, NHID=512, BR=32, DEPTH=3, V=32768.
// bucket g = lab>>5. node0=0 (step g>>5), node1=1+(g>>5) (step g&31),
// node2=33+g (step lab&31). out[b] = prod_k softmax(x_b @ W[node_k])[step_k]
//
// R14: R10-R13 all measure ~0.25 GB/s per resident wave regardless of
// structure (reg dbuf, LDS-DMA pipeline, hermetic asm, 4-wave TLP): per-wave
// streams are serialized at ~1.2-1.5K cy per load chain and every MLP
// attempt paid more in occupancy (VGPR 160-192, LDS 42-54 KB -> 6-9
// waves/CU) than it gained. R14 pulls the one unpulled lever: residency.
// Same bucket-per-block algorithm, footprint-minimized:
//  - no W register buffering: wv = wp[ii*64] consumed immediately
//    (acc[8] float4 = 32 regs), __launch_bounds__(192,6) caps VGPR at 85.
//  - x staged via global_load_lds width-16 into xs[s][h] (lane-linear dest,
//    2 DMAs/sample row instead of 16 serialized register loads; the
//    __syncthreads drain after staging is mandatory anyway).
//  - LDS ~16.5 KB, 8 blocks/CU x 3 waves = 24 waves/CU (3-4x R10/R13).
// FMA-loop x reads: 8 x ds_read_b32, 8 distinct banks (hsel groups),
// same-address broadcast across colg -> conflict-free.

#define NHID  512
#define BR    32
#define BATCH 4096
#define NBUCK 1024
#define SMAX  8
#define CAP   32    // Poisson(4) max ~16

#define FMA4(A, xv, wv_) do { \
    (A).x = fmaf((xv), (wv_).x, (A).x); \
    (A).y = fmaf((xv), (wv_).y, (A).y); \
    (A).z = fmaf((xv), (wv_).z, (A).z); \
    (A).w = fmaf((xv), (wv_).w, (A).w); } while (0)

// async global->LDS, 16 B per lane: HW writes lds_base + lane*16 (linear),
// global source address is per-lane.
__device__ __forceinline__ void gload_lds16(const float* g, float* l) {
    __builtin_amdgcn_global_load_lds(
        (const __attribute__((address_space(1))) void*)g,
        (__attribute__((address_space(3))) void*)l, 16, 0, 0);
}

__global__ __launch_bounds__(192, 6) void hsm_bucket(
    const float* __restrict__ inputs,
    const int* __restrict__ labels,
    const float* __restrict__ W,
    float* __restrict__ out)
{
    __shared__ float xs[SMAX][NHID];    // 16 KB, [s][h]
    __shared__ float pk[3][SMAX];
    __shared__ int   sids[CAP];
    __shared__ int   slab[CAP];
    __shared__ int   scnt;

    const int g    = blockIdx.x;
    const int tid  = threadIdx.x;
    const int k    = tid >> 6;     // wave = tree level
    const int lane = tid & 63;
    const int colg = lane & 7;     // float4 column group
    const int hsel = lane >> 3;    // h strip: h = hsel + 8*ii

    const int node   = (k == 0) ? 0 : (k == 1) ? 1 + (g >> 5) : 33 + g;
    const int step01 = (k == 0) ? (g >> 5) : (g & 31);

    // lane (hsel,colg) reads W row (hsel+8*ii), bytes colg*16..+16:
    // the wave covers 8 contiguous rows = 1 KB per iteration, coalesced.
    const float4* wp = (const float4*)(W + (size_t)node * (NHID * BR))
                       + hsel * 8 + colg;

    if (tid == 0) scnt = 0;
    __syncthreads();

    // ---- self-discovery: scan all labels as int4, compact matches ----
    const int4* l4 = (const int4*)labels;
    for (int i = tid; i < BATCH / 4; i += 192) {
        const int4 v = l4[i];
        if ((v.x >> 5) == g) { int p = atomicAdd(&scnt, 1); if (p < CAP) { sids[p] = 4*i;   slab[p] = v.x; } }
        if ((v.y >> 5) == g) { int p = atomicAdd(&scnt, 1); if (p < CAP) { sids[p] = 4*i+1; slab[p] = v.y; } }
        if ((v.z >> 5) == g) { int p = atomicAdd(&scnt, 1); if (p < CAP) { sids[p] = 4*i+2; slab[p] = v.z; } }
        if ((v.w >> 5) == g) { int p = atomicAdd(&scnt, 1); if (p < CAP) { sids[p] = 4*i+3; slab[p] = v.w; } }
    }
    __syncthreads();
    const int mt = min(scnt, CAP);
    if (mt == 0) return;    // no DMAs issued yet: clean exit

    for (int c0 = 0; c0 < mt; c0 += SMAX) {
        // ---- stage xs[s][h] via async DMA; wave k stages s = k, k+3, k+6.
        // Padded slots re-stage a valid row (finite garbage, never read out).
        for (int s = k; s < SMAX; s += 3) {
            const int q = c0 + s;
            const float* src = inputs
                + (size_t)sids[(q < mt) ? q : c0] * NHID + lane * 4;
            gload_lds16(src,       &xs[s][0]);
            gload_lds16(src + 256, &xs[s][256]);
        }
        __syncthreads();   // drains each wave's DMAs (vmcnt 0) + barrier

        float4 acc[SMAX];
        #pragma unroll
        for (int s = 0; s < SMAX; ++s) acc[s] = make_float4(0, 0, 0, 0);

        // ---- W stream: 64 x (1 KB/wave coalesced load -> 32 FMA) ----
        #pragma unroll 8
        for (int ii = 0; ii < 64; ++ii) {
            const float4 wv = wp[ii * 64];
            const int h = hsel + 8 * ii;
            float xv[SMAX];
            #pragma unroll
            for (int s = 0; s < SMAX; ++s) xv[s] = xs[s][h];
            FMA4(acc[0], xv[0], wv); FMA4(acc[1], xv[1], wv);
            FMA4(acc[2], xv[2], wv); FMA4(acc[3], xv[3], wv);
            FMA4(acc[4], xv[4], wv); FMA4(acc[5], xv[5], wv);
            FMA4(acc[6], xv[6], wv); FMA4(acc[7], xv[7], wv);
        }

        // butterfly-reduce over hsel (masks 8,16,32): all lanes full sums
        #pragma unroll
        for (int s = 0; s < SMAX; ++s) {
            #pragma unroll
            for (int mm = 8; mm <= 32; mm <<= 1) {
                acc[s].x += __shfl_xor(acc[s].x, mm);
                acc[s].y += __shfl_xor(acc[s].y, mm);
                acc[s].z += __shfl_xor(acc[s].z, mm);
                acc[s].w += __shfl_xor(acc[s].w, mm);
            }
        }

        // per-sample softmax over 32 logits (8 colg lanes x 4 comps)
        #pragma unroll
        for (int s = 0; s < SMAX; ++s) {
            float4 a = acc[s];
            float mx = fmaxf(fmaxf(a.x, a.y), fmaxf(a.z, a.w));
            #pragma unroll
            for (int mm = 1; mm <= 4; mm <<= 1) mx = fmaxf(mx, __shfl_xor(mx, mm));
            float es = expf(a.x - mx) + expf(a.y - mx) + expf(a.z - mx) + expf(a.w - mx);
            #pragma unroll
            for (int mm = 1; mm <= 4; mm <<= 1) es += __shfl_xor(es, mm);

            const int step = (k == 2) ? (slab[c0 + s] & 31) : step01;
            const int e = step & 3;
            const float vv = (e == 0) ? a.x : (e == 1) ? a.y : (e == 2) ? a.z : a.w;
            const float sl = __shfl(vv, step >> 2);
            const float p = expf(sl - mx) / es;
            if (lane == 0) pk[k][s] = p;
        }
        __syncthreads();

        if (tid < SMAX && c0 + tid < mt)
            out[sids[c0 + tid]] = pk[0][tid] * pk[1][tid] * pk[2][tid];
        __syncthreads();   // all reads of xs/pk done before next pass restages
    }
}

extern "C" void kernel_launch(void* const* d_in, const int* in_sizes, int n_in,
                              void* d_out, int out_size, void* d_ws, size_t ws_size,
                              hipStream_t stream)
{
    const float* inputs = (const float*)d_in[0];
    const int*   labels = (const int*)d_in[1];
    const float* W      = (const float*)d_in[2];
    float* out = (float*)d_out;

    hsm_bucket<<<dim3(NBUCK), dim3(192), 0, stream>>>(inputs, labels, W, out);
}

// Round 6
// 136.126 us; speedup vs baseline: 1.3456x; 1.2331x over previous
//
#include <hip/hip_runtime.h>

// Hierarchical softmax: B=4096, NHID=512, BR=32, DEPTH=3, V=32768.
// bucket g = lab>>5. node0=0 (step g>>5), node1=1+(g>>5) (step g&31),
// node2=33+g (step lab&31). out[b] = prod_k softmax(x_b @ W[node_k])[step_k]
//
// R15: R10-R14 all pinned at ~0.4-0.6 TB/s because every structure gave
// each WAVE a private serial W-load chain (compiler holds ~1 load in
// flight; launch-bounds pressure in R14 even caused 13.7 MB of spill
// writes). R15 makes the BLOCK the streaming unit (m97 pattern): all three
// levels' W (3x64 KB) flow through shared triple-buffered 8 KB LDS steps
// via dense global_load_lds bursts; raw s_barrier + counted vmcnt(4)
// (T3/T4) keeps 2 steps in flight; consumption is cooperative (waves split
// rows, lane=(s,colgroup), ds_read_b128 8-way broadcast conflict-free).
// Per-level partials reduce through LDS at level end with an inline
// 32-lane shuffle softmax. acc = one float4/lane -> VGPR ~60, no spills;
// LDS ~46 KB -> 3 blocks/CU; per-block serial = 24 steps, not 64 loads.

#define NHID  512
#define BR    32
#define BATCH 4096
#define NBUCK 1024
#define SMAX  8
#define CAP   32               // Poisson(4) max ~16
#define SFLT  2048             // floats per step = 64 rows x 32 cols (8 KB)
#define NSTEP 24               // 3 levels x 8 steps
#define XPAD  520              // xs row stride: 2080 B, 16B-aligned, bank-safe

#define FMA4(A, xv, wv_) do { \
    (A).x = fmaf((xv), (wv_).x, (A).x); \
    (A).y = fmaf((xv), (wv_).y, (A).y); \
    (A).z = fmaf((xv), (wv_).z, (A).z); \
    (A).w = fmaf((xv), (wv_).w, (A).w); } while (0)

// async global->LDS, 16 B per lane: HW writes lds_base + lane*16 (linear),
// global source address is per-lane. (Verified in R14: bench passed.)
__device__ __forceinline__ void gload_lds16(const float* g, float* l) {
    __builtin_amdgcn_global_load_lds(
        (const __attribute__((address_space(1))) void*)g,
        (__attribute__((address_space(3))) void*)l, 16, 0, 0);
}

__global__ __launch_bounds__(256) void hsm_bucket(
    const float* __restrict__ inputs,
    const int* __restrict__ labels,
    const float* __restrict__ W,
    float* __restrict__ out)
{
    __shared__ float xs[SMAX][XPAD];    // 16.6 KB: [s][h], padded stride
    __shared__ float wbuf[3][SFLT];     // 24 KB: shared W step ring
    __shared__ float part[4 * 256];     // 4 KB: per-wave partial logits
    __shared__ float pk[3][SMAX];
    __shared__ int   sids[CAP];
    __shared__ int   slab[CAP];
    __shared__ int   scnt;

    const int g    = blockIdx.x;
    const int tid  = threadIdx.x;
    const int w    = tid >> 6;     // wave 0..3
    const int lane = tid & 63;
    const int s8   = lane >> 3;    // sample 0..7
    const int cg   = lane & 7;     // float4 column group 0..7

    if (tid == 0) scnt = 0;
    __syncthreads();

    // ---- self-discovery: scan all labels as int4, compact matches ----
    const int4* l4 = (const int4*)labels;
    #pragma unroll
    for (int r = 0; r < BATCH / 4 / 256; ++r) {
        const int i = tid + 256 * r;
        const int4 v = l4[i];
        if ((v.x >> 5) == g) { int p = atomicAdd(&scnt, 1); if (p < CAP) { sids[p] = 4*i;   slab[p] = v.x; } }
        if ((v.y >> 5) == g) { int p = atomicAdd(&scnt, 1); if (p < CAP) { sids[p] = 4*i+1; slab[p] = v.y; } }
        if ((v.z >> 5) == g) { int p = atomicAdd(&scnt, 1); if (p < CAP) { sids[p] = 4*i+2; slab[p] = v.z; } }
        if ((v.w >> 5) == g) { int p = atomicAdd(&scnt, 1); if (p < CAP) { sids[p] = 4*i+3; slab[p] = v.w; } }
    }
    __syncthreads();
    const int mt = min(scnt, CAP);
    if (mt == 0) return;    // no DMAs issued yet: clean exit

    const size_t nb0 = 0;
    const size_t nb1 = (size_t)(1 + (g >> 5)) * (NHID * BR);
    const size_t nb2 = (size_t)(33 + g) * (NHID * BR);

    // stage 8 KB step t2 of the 24-step W stream into wbuf[b].
    // 2 DMA instrs per wave; layout is linear: wbuf[b][f] = Wnode[base + f].
    #define ISSUE(t2, b) do { \
        const int kk_ = (t2) >> 3; \
        const size_t nb_ = (kk_ == 0) ? nb0 : (kk_ == 1) ? nb1 : nb2; \
        const float* s_ = W + nb_ + (size_t)((t2) & 7) * SFLT + tid * 4; \
        float* d_ = &wbuf[(b)][w * 256]; \
        gload_lds16(s_,        d_); \
        gload_lds16(s_ + 1024, d_ + 1024); } while (0)

    for (int c0 = 0; c0 < mt; c0 += SMAX) {
        // ---- x-stage via DMA: wave w stages samples 2w, 2w+1
        //      (pad slots restage row c0: valid, never read out) ----
        #pragma unroll
        for (int e = 0; e < 2; ++e) {
            const int sl = 2 * w + e;
            const int q  = c0 + sl;
            const float* src = inputs
                + (size_t)sids[(q < mt) ? q : c0] * NHID + lane * 4;
            gload_lds16(src,       &xs[sl][0]);
            gload_lds16(src + 256, &xs[sl][256]);
        }
        ISSUE(0, 0);
        ISSUE(1, 1);
        __syncthreads();        // drains all DMAs: xs + steps 0,1 ready

        float4 acc = make_float4(0.f, 0.f, 0.f, 0.f);

        #pragma unroll
        for (int t = 0; t < NSTEP; ++t) {
            if (t > 0) {
                // all reads of buf[(t+2)%3] (= step t-1's buffer) complete
                asm volatile("s_waitcnt lgkmcnt(0)" ::: "memory");
                __builtin_amdgcn_s_barrier();
            }
            if (t + 2 < NSTEP) ISSUE(t + 2, (t + 2) % 3);
            // counted wait: step t complete, t+1/t+2 (2 instrs each) in flight
            if (t < NSTEP - 2)       { asm volatile("s_waitcnt vmcnt(4)" ::: "memory"); }
            else if (t == NSTEP - 2) { asm volatile("s_waitcnt vmcnt(2)" ::: "memory"); }
            else                     { asm volatile("s_waitcnt vmcnt(0)" ::: "memory"); }
            __builtin_amdgcn_sched_barrier(0);

            // ---- consume step t: waves split 64 rows, 16 each ----
            const float4* wb4 = (const float4*)wbuf[t % 3];
            const int tl = t & 7;
            #pragma unroll
            for (int r0 = 0; r0 < 16; ++r0) {
                const int row = w * 16 + r0;
                const float4 wv = wb4[row * 8 + cg];       // 8-way broadcast
                const float  xv = xs[s8][tl * 64 + row];   // 2-way bank, free
                FMA4(acc, xv, wv);
            }

            // ---- level end: reduce partials + inline softmax ----
            if ((t & 7) == 7) {
                ((float4*)part)[tid] = acc;
                __syncthreads();   // drains vmcnt too (3x/pass, accepted)
                const int ss = tid >> 5, cc = tid & 31;
                float v = 0.f;
                #pragma unroll
                for (int w2 = 0; w2 < 4; ++w2)
                    v += part[w2 * 256 + (ss * 8 + (cc >> 2)) * 4 + (cc & 3)];
                float mx = v;
                #pragma unroll
                for (int mm = 1; mm <= 16; mm <<= 1) mx = fmaxf(mx, __shfl_xor(mx, mm));
                const float e = expf(v - mx);
                float es = e;
                #pragma unroll
                for (int mm = 1; mm <= 16; mm <<= 1) es += __shfl_xor(es, mm);
                const int kk = t >> 3;
                const int step = (kk == 2) ? (slab[c0 + ss] & 31)
                               : (kk == 0) ? (g >> 5) : (g & 31);
                if (cc == step) pk[kk][ss] = e / es;
                acc = make_float4(0.f, 0.f, 0.f, 0.f);
            }
        }
        __syncthreads();   // pk visible to all

        if (tid < SMAX && c0 + tid < mt)
            out[sids[c0 + tid]] = pk[0][tid] * pk[1][tid] * pk[2][tid];
        __syncthreads();   // protect xs/pk before next pass restages
    }
    #undef ISSUE
}

extern "C" void kernel_launch(void* const* d_in, const int* in_sizes, int n_in,
                              void* d_out, int out_size, void* d_ws, size_t ws_size,
                              hipStream_t stream)
{
    const float* inputs = (const float*)d_in[0];
    const int*   labels = (const int*)d_in[1];
    const float* W      = (const float*)d_in[2];
    float* out = (float*)d_out;

    hsm_bucket<<<dim3(NBUCK), dim3(256), 0, stream>>>(inputs, labels, W, out);
}